// Round 3
// baseline (332.487 us; speedup 1.0000x reference)
//
#include <hip/hip_runtime.h>
#include <float.h>
#include <math.h>

// Problem constants (from reference)
#define NA_LOG2 20                    // NA = 1048576
#define NB_ 4
#define ROWS (NB_ << NA_LOG2)         // 4194304 rows of probs (3 floats each)
#define B1 2048                       // blocks (512 per batch)
#define T1 256
#define ROWS_PER_BLOCK (ROWS / B1)    // 2048
#define BLOCKS_PER_BATCH (B1 / NB_)   // 512
#define ROWS_PER_THREAD 8             // 8 rows = 96 B = 6 float4 per thread

// ws layout: wsS [0,32KB) floats, wsI [32KB,64KB) ints, counter at 64KB
#define WS_I_OFF   (B1 * 4 * sizeof(float))
#define WS_COUNTER_OFF (64 * 1024)

// strict total order: higher score wins, ties -> lower flat index
__device__ __forceinline__ bool better(float sa, int ia, float sb, int ib) {
    return (sa > sb) || ((sa == sb) && (ia < ib));
}

// merge sorted top2 (b1>=b2) into sorted top2 (a1>=a2)
__device__ __forceinline__ void merge2(float& a1s, int& a1i, float& a2s, int& a2i,
                                       float b1s, int b1i, float b2s, int b2i)
{
    if (better(b1s, b1i, a1s, a1i)) {
        if (better(a1s, a1i, b2s, b2i)) { a2s = a1s; a2i = a1i; }
        else                            { a2s = b2s; a2i = b2i; }
        a1s = b1s; a1i = b1i;
    } else if (better(b1s, b1i, a2s, a2i)) {
        a2s = b1s; a2i = b1i;
    }
}

#define UPD(sa, ia, sb, ib, s, i)                                        \
    do {                                                                 \
        if (better((s), (i), (sa), (ia))) {                              \
            (sb) = (sa); (ib) = (ia); (sa) = (s); (ia) = (i);            \
        } else if (better((s), (i), (sb), (ib))) {                       \
            (sb) = (s); (ib) = (i);                                      \
        }                                                                \
    } while (0)

// Fused: per-block top-2 (class1, class2), publish to ws, last block finishes.
// MLP: each thread loads its full 96B segment (6 x float4) into registers
// BEFORE consuming -> 6 loads in flight per thread. (Round-2 kernel had
// VGPR_Count=16 -> compiler serialized to 1 load in flight -> 441 GB/s.)
__global__ __launch_bounds__(T1, 4) void topk_fused(const float* __restrict__ probs,
                                                    const float* __restrict__ anchors,
                                                    const float* __restrict__ deltas,
                                                    float* __restrict__ wsS,
                                                    int* __restrict__ wsI,
                                                    unsigned int* __restrict__ counter,
                                                    float* __restrict__ out)
{
    const int tid = threadIdx.x;
    const int bb = blockIdx.x;

    float s1a = -FLT_MAX, s1b = -FLT_MAX, s2a = -FLT_MAX, s2b = -FLT_MAX;
    int   i1a = 0x7fffffff, i1b = 0x7fffffff, i2a = 0x7fffffff, i2b = 0x7fffffff;

    const int row0 = bb * ROWS_PER_BLOCK + tid * ROWS_PER_THREAD;
    const float4* p = (const float4*)probs + ((row0 * 3) >> 2);  // 96B-aligned segment

    // ---- issue all 6 loads before any consume ----
    float f[24];
#pragma unroll
    for (int j = 0; j < 6; ++j) {
        ((float4*)f)[j] = p[j];
    }

    // rows r=0..7; float index of row r, class c is 3r+c; fg flat index = row*2 + (c-1)
    const int f0 = row0 * 2;
#pragma unroll
    for (int r = 0; r < 8; ++r) {
        UPD(s1a, i1a, s1b, i1b, f[3 * r + 1], f0 + 2 * r);       // class1
        UPD(s2a, i2a, s2b, i2b, f[3 * r + 2], f0 + 2 * r + 1);   // class2
    }

    // wave (64-lane) butterfly reduce of both top2 structs
#pragma unroll
    for (int m = 1; m < 64; m <<= 1) {
        float o1s = __shfl_xor(s1a, m); int o1i = __shfl_xor(i1a, m);
        float o2s = __shfl_xor(s1b, m); int o2i = __shfl_xor(i1b, m);
        merge2(s1a, i1a, s1b, i1b, o1s, o1i, o2s, o2i);
        o1s = __shfl_xor(s2a, m); o1i = __shfl_xor(i2a, m);
        o2s = __shfl_xor(s2b, m); o2i = __shfl_xor(i2b, m);
        merge2(s2a, i2a, s2b, i2b, o1s, o1i, o2s, o2i);
    }

    __shared__ float ls[4][4];
    __shared__ int   li[4][4];
    __shared__ int   amLast;
    const int wave = tid >> 6, lane = tid & 63;
    if (lane == 0) {
        ls[wave][0] = s1a; li[wave][0] = i1a;
        ls[wave][1] = s1b; li[wave][1] = i1b;
        ls[wave][2] = s2a; li[wave][2] = i2a;
        ls[wave][3] = s2b; li[wave][3] = i2b;
    }
    __syncthreads();
    if (tid == 0) {
        for (int wv = 1; wv < 4; ++wv) {
            merge2(s1a, i1a, s1b, i1b, ls[wv][0], li[wv][0], ls[wv][1], li[wv][1]);
            merge2(s2a, i2a, s2b, i2b, ls[wv][2], li[wv][2], ls[wv][3], li[wv][3]);
        }
        const int base = bb * 4;
        // agent-scope stores: visible across XCDs for the last block's read
        __hip_atomic_store(&wsS[base + 0], s1a, __ATOMIC_RELAXED, __HIP_MEMORY_SCOPE_AGENT);
        __hip_atomic_store(&wsI[base + 0], i1a, __ATOMIC_RELAXED, __HIP_MEMORY_SCOPE_AGENT);
        __hip_atomic_store(&wsS[base + 1], s1b, __ATOMIC_RELAXED, __HIP_MEMORY_SCOPE_AGENT);
        __hip_atomic_store(&wsI[base + 1], i1b, __ATOMIC_RELAXED, __HIP_MEMORY_SCOPE_AGENT);
        __hip_atomic_store(&wsS[base + 2], s2a, __ATOMIC_RELAXED, __HIP_MEMORY_SCOPE_AGENT);
        __hip_atomic_store(&wsI[base + 2], i2a, __ATOMIC_RELAXED, __HIP_MEMORY_SCOPE_AGENT);
        __hip_atomic_store(&wsS[base + 3], s2b, __ATOMIC_RELAXED, __HIP_MEMORY_SCOPE_AGENT);
        __hip_atomic_store(&wsI[base + 3], i2b, __ATOMIC_RELAXED, __HIP_MEMORY_SCOPE_AGENT);
        __threadfence();  // release our results before signaling
        unsigned int old = __hip_atomic_fetch_add(counter, 1u, __ATOMIC_ACQ_REL,
                                                  __HIP_MEMORY_SCOPE_AGENT);
        amLast = (old == (unsigned)(B1 - 1)) ? 1 : 0;
    }
    __syncthreads();
    if (!amLast) return;

    // ===== last block: final reduce over B1*4 candidates, sort, epilogue =====
    __threadfence();  // acquire side

    __shared__ float g_s[16];
    __shared__ int   g_i[16];

    // 4 waves, each handles 2 of the 8 (batch,class) groups; 1024 candidates/group
#pragma unroll
    for (int grp2 = 0; grp2 < 2; ++grp2) {
        const int g = wave * 2 + grp2;
        const int batch = g >> 1, clsbit = g & 1;
        float sa = -FLT_MAX, sb = -FLT_MAX;
        int   ia = 0x7fffffff, ib = 0x7fffffff;
#pragma unroll
        for (int j = 0; j < (2 * BLOCKS_PER_BATCH) / 64; ++j) {  // 16 candidates/lane
            const int q = lane + j * 64;                          // 0..1023
            const int blk = batch * BLOCKS_PER_BATCH + (q >> 1);
            const int e = q & 1;
            const int idx = blk * 4 + clsbit * 2 + e;
            const float s = __hip_atomic_load(&wsS[idx], __ATOMIC_RELAXED,
                                              __HIP_MEMORY_SCOPE_AGENT);
            const int   i = __hip_atomic_load(&wsI[idx], __ATOMIC_RELAXED,
                                              __HIP_MEMORY_SCOPE_AGENT);
            UPD(sa, ia, sb, ib, s, i);
        }
#pragma unroll
        for (int m = 1; m < 64; m <<= 1) {
            float o1s = __shfl_xor(sa, m); int o1i = __shfl_xor(ia, m);
            float o2s = __shfl_xor(sb, m); int o2i = __shfl_xor(ib, m);
            merge2(sa, ia, sb, ib, o1s, o1i, o2s, o2i);
        }
        if (lane == 0) {
            g_s[g * 2 + 0] = sa; g_i[g * 2 + 0] = ia;
            g_s[g * 2 + 1] = sb; g_i[g * 2 + 1] = ib;
        }
    }
    __syncthreads();

    if (tid == 0) {
        // insertion sort, descending by (score, -idx) == the reference keep-order
        for (int a = 1; a < 16; ++a) {
            float s = g_s[a]; int ix = g_i[a];
            int b = a - 1;
            while (b >= 0 && better(s, ix, g_s[b], g_i[b])) {
                g_s[b + 1] = g_s[b]; g_i[b + 1] = g_i[b]; --b;
            }
            g_s[b + 1] = s; g_i[b + 1] = ix;
        }
    }
    __syncthreads();

    if (tid < 16) {
        const float scale[6] = {256.f, 256.f, 256.f, 256.f, 128.f, 128.f};
        const float stdv[6]  = {0.1f, 0.1f, 0.1f, 0.2f, 0.2f, 0.2f};
        const int flat = g_i[tid];
        const float score = g_s[tid];
        const int prop = flat >> 1;
        const int cls = (flat & 1) + 1;
        const int b = prop >> NA_LOG2;
        const int ar = prop & ((1 << NA_LOG2) - 1);   // anchors_rep index mod NA

        float anc[6], dlt[6];
#pragma unroll
        for (int k = 0; k < 6; ++k) {
            anc[k] = floorf(anchors[ar * 6 + k] / scale[k]);
            dlt[k] = deltas[prop * 6 + k] * stdv[k];
        }
        float h = anc[2] - anc[0];
        float w = anc[3] - anc[1];
        float d = anc[5] - anc[4];
        float cy = anc[0] + 0.5f * h + dlt[0] * h;
        float cx = anc[1] + 0.5f * w + dlt[1] * w;
        float cz = anc[4] + 0.5f * d + dlt[2] * d;
        h *= expf(dlt[3]);
        w *= expf(dlt[4]);
        d *= expf(dlt[5]);
        const float y1 = cy - 0.5f * h, x1 = cx - 0.5f * w, z1 = cz - 0.5f * d;
        const float box[6] = {y1, x1, y1 + h, x1 + w, z1, z1 + d};

        float* o = out + tid * 9;
#pragma unroll
        for (int k = 0; k < 6; ++k) {
            float bx = box[k] * scale[k];
            bx = fminf(fmaxf(bx, 0.f), scale[k]);
            o[k] = rintf(bx);               // jnp.round = round-half-to-even
        }
        o[6] = (float)b;
        o[7] = (float)cls;
        o[8] = score;
    }
}

extern "C" void kernel_launch(void* const* d_in, const int* in_sizes, int n_in,
                              void* d_out, int out_size, void* d_ws, size_t ws_size,
                              hipStream_t stream)
{
    // setup_inputs order: anchors, probs, deltas, batch_ixs
    const float* anchors = (const float*)d_in[0];
    const float* probs   = (const float*)d_in[1];
    const float* deltas  = (const float*)d_in[2];
    // batch_ixs (d_in[3]) is closed-form (prop >> 20); unused.

    float*        wsS     = (float*)d_ws;
    int*          wsI     = (int*)((char*)d_ws + WS_I_OFF);
    unsigned int* counter = (unsigned int*)((char*)d_ws + WS_COUNTER_OFF);

    // zero the completion counter (ws is poisoned 0xAA before every launch)
    hipMemsetAsync(counter, 0, sizeof(unsigned int), stream);

    topk_fused<<<dim3(B1), dim3(T1), 0, stream>>>(probs, anchors, deltas,
                                                  wsS, wsI, counter, (float*)d_out);
}

// Round 4
// 245.607 us; speedup vs baseline: 1.3537x; 1.3537x over previous
//
#include <hip/hip_runtime.h>
#include <float.h>
#include <math.h>

// Problem constants (from reference)
#define NA_LOG2 20                    // NA = 1048576
#define NB_ 4
#define ROWS (NB_ << NA_LOG2)         // 4194304 rows of probs (3 floats each)
#define B1 1024                       // blocks (256 per batch)
#define T1 256
#define ROWS_PER_BLOCK (ROWS / B1)    // 4096
#define SEGS_PER_BLOCK (ROWS_PER_BLOCK / 4)  // 1024 segments of 4 rows (48B)
#define BLOCKS_PER_BATCH (B1 / NB_)   // 256

// ws layout: wsS [0,16KB) floats, wsI [16KB,32KB) ints, counter at 32KB
#define WS_I_OFF       (B1 * 4 * sizeof(float))
#define WS_COUNTER_OFF (32 * 1024)

// strict total order: higher score wins, ties -> lower flat index
__device__ __forceinline__ bool better(float sa, int ia, float sb, int ib) {
    return (sa > sb) || ((sa == sb) && (ia < ib));
}

// BRANCHLESS top-2 insert: pure cndmask dataflow so global loads can be
// clustered across the whole body (round-2/3 branchy version chopped the
// kernel into basic blocks -> loads serialized -> 440 GB/s).
__device__ __forceinline__ void upd(float& sa, int& ia, float& sb, int& ib,
                                    float s, int i)
{
    const bool b1 = better(s, i, sa, ia);   // beats first
    const bool b2 = better(s, i, sb, ib);   // beats second
    const float nbs = b1 ? sa : (b2 ? s : sb);
    const int   nbi = b1 ? ia : (b2 ? i : ib);
    sa = b1 ? s : sa;
    ia = b1 ? i : ia;
    sb = nbs;
    ib = nbi;
}

// BRANCHLESS merge of sorted pair (b1>=b2) into sorted pair (a1>=a2)
__device__ __forceinline__ void merge2(float& a1s, int& a1i, float& a2s, int& a2i,
                                       float b1s, int b1i, float b2s, int b2i)
{
    const bool t = better(b1s, b1i, a1s, a1i);
    const float n1s = t ? b1s : a1s;  const int n1i = t ? b1i : a1i;
    const float c1s = t ? a1s : b1s;  const int c1i = t ? a1i : b1i;  // loser of firsts
    const float c2s = t ? b2s : a2s;  const int c2i = t ? b2i : a2i;  // winner's second
    const bool u = better(c1s, c1i, c2s, c2i);
    a1s = n1s;               a1i = n1i;
    a2s = u ? c1s : c2s;     a2i = u ? c1i : c2i;
}

// Fused: per-block top-2 (class1, class2), publish to ws, last block finishes.
__global__ __launch_bounds__(T1, 4) void topk_fused(const float* __restrict__ probs,
                                                    const float* __restrict__ anchors,
                                                    const float* __restrict__ deltas,
                                                    float* __restrict__ wsS,
                                                    int* __restrict__ wsI,
                                                    unsigned int* __restrict__ counter,
                                                    float* __restrict__ out)
{
    const int tid = threadIdx.x;
    const int bb = blockIdx.x;

    float s1a = -FLT_MAX, s1b = -FLT_MAX, s2a = -FLT_MAX, s2b = -FLT_MAX;
    int   i1a = 0x7fffffff, i1b = 0x7fffffff, i2a = 0x7fffffff, i2b = 0x7fffffff;

    const float4* p4 = (const float4*)probs;
    const int s_base = bb * SEGS_PER_BLOCK;

    // ---- issue ALL 12 loads (4 segments x 3 float4) before any consume ----
    // float4 array with constant post-unroll indices: SROA-promoted to regs
    // (round-3's float[24] + float4* cast defeated SROA -> 50MB scratch spill).
    float4 v[12];
#pragma unroll
    for (int k = 0; k < 4; ++k) {
        const int seg = s_base + k * T1 + tid;       // 4 rows = 48B per segment
        const float4* p = p4 + seg * 3;
        v[3 * k + 0] = p[0];
        v[3 * k + 1] = p[1];
        v[3 * k + 2] = p[2];
    }

    // ---- consume: float index within segment 0..11, row=idx/3, col=idx%3 ----
#pragma unroll
    for (int k = 0; k < 4; ++k) {
        const int seg = s_base + k * T1 + tid;
        const int f0 = seg * 8;                      // 4 rows x 2 fg classes
        const float4 a = v[3 * k + 0];
        const float4 b = v[3 * k + 1];
        const float4 c = v[3 * k + 2];
        upd(s1a, i1a, s1b, i1b, a.y, f0 + 0);   // r0 class1
        upd(s2a, i2a, s2b, i2b, a.z, f0 + 1);   // r0 class2
        upd(s1a, i1a, s1b, i1b, b.x, f0 + 2);   // r1 class1
        upd(s2a, i2a, s2b, i2b, b.y, f0 + 3);   // r1 class2
        upd(s1a, i1a, s1b, i1b, b.w, f0 + 4);   // r2 class1
        upd(s2a, i2a, s2b, i2b, c.x, f0 + 5);   // r2 class2
        upd(s1a, i1a, s1b, i1b, c.z, f0 + 6);   // r3 class1
        upd(s2a, i2a, s2b, i2b, c.w, f0 + 7);   // r3 class2
    }

    // wave (64-lane) butterfly reduce of both top2 structs (branchless merges)
#pragma unroll
    for (int m = 1; m < 64; m <<= 1) {
        float o1s = __shfl_xor(s1a, m); int o1i = __shfl_xor(i1a, m);
        float o2s = __shfl_xor(s1b, m); int o2i = __shfl_xor(i1b, m);
        merge2(s1a, i1a, s1b, i1b, o1s, o1i, o2s, o2i);
        o1s = __shfl_xor(s2a, m); o1i = __shfl_xor(i2a, m);
        o2s = __shfl_xor(s2b, m); o2i = __shfl_xor(i2b, m);
        merge2(s2a, i2a, s2b, i2b, o1s, o1i, o2s, o2i);
    }

    __shared__ float ls[4][4];
    __shared__ int   li[4][4];
    __shared__ int   amLast;
    const int wave = tid >> 6, lane = tid & 63;
    if (lane == 0) {
        ls[wave][0] = s1a; li[wave][0] = i1a;
        ls[wave][1] = s1b; li[wave][1] = i1b;
        ls[wave][2] = s2a; li[wave][2] = i2a;
        ls[wave][3] = s2b; li[wave][3] = i2b;
    }
    __syncthreads();
    if (tid == 0) {
        for (int wv = 1; wv < 4; ++wv) {
            merge2(s1a, i1a, s1b, i1b, ls[wv][0], li[wv][0], ls[wv][1], li[wv][1]);
            merge2(s2a, i2a, s2b, i2b, ls[wv][2], li[wv][2], ls[wv][3], li[wv][3]);
        }
        const int base = bb * 4;
        // agent-scope stores: visible across XCDs for the last block's read
        __hip_atomic_store(&wsS[base + 0], s1a, __ATOMIC_RELAXED, __HIP_MEMORY_SCOPE_AGENT);
        __hip_atomic_store(&wsI[base + 0], i1a, __ATOMIC_RELAXED, __HIP_MEMORY_SCOPE_AGENT);
        __hip_atomic_store(&wsS[base + 1], s1b, __ATOMIC_RELAXED, __HIP_MEMORY_SCOPE_AGENT);
        __hip_atomic_store(&wsI[base + 1], i1b, __ATOMIC_RELAXED, __HIP_MEMORY_SCOPE_AGENT);
        __hip_atomic_store(&wsS[base + 2], s2a, __ATOMIC_RELAXED, __HIP_MEMORY_SCOPE_AGENT);
        __hip_atomic_store(&wsI[base + 2], i2a, __ATOMIC_RELAXED, __HIP_MEMORY_SCOPE_AGENT);
        __hip_atomic_store(&wsS[base + 3], s2b, __ATOMIC_RELAXED, __HIP_MEMORY_SCOPE_AGENT);
        __hip_atomic_store(&wsI[base + 3], i2b, __ATOMIC_RELAXED, __HIP_MEMORY_SCOPE_AGENT);
        __threadfence();  // release before signaling
        unsigned int old = __hip_atomic_fetch_add(counter, 1u, __ATOMIC_ACQ_REL,
                                                  __HIP_MEMORY_SCOPE_AGENT);
        amLast = (old == (unsigned)(B1 - 1)) ? 1 : 0;
    }
    __syncthreads();
    if (!amLast) return;

    // ===== last block: final reduce over B1*4 candidates, sort, epilogue =====
    __threadfence();  // acquire side

    __shared__ float g_s[16];
    __shared__ int   g_i[16];

    // 4 waves, each handles 2 of the 8 (batch,class) groups; 512 candidates/group
#pragma unroll
    for (int grp2 = 0; grp2 < 2; ++grp2) {
        const int g = wave * 2 + grp2;
        const int batch = g >> 1, clsbit = g & 1;
        float sa = -FLT_MAX, sb = -FLT_MAX;
        int   ia = 0x7fffffff, ib = 0x7fffffff;
#pragma unroll
        for (int j = 0; j < (2 * BLOCKS_PER_BATCH) / 64; ++j) {  // 8 candidates/lane
            const int q = lane + j * 64;                          // 0..511
            const int blk = batch * BLOCKS_PER_BATCH + (q >> 1);
            const int e = q & 1;
            const int idx = blk * 4 + clsbit * 2 + e;
            const float s = __hip_atomic_load(&wsS[idx], __ATOMIC_RELAXED,
                                              __HIP_MEMORY_SCOPE_AGENT);
            const int   i = __hip_atomic_load(&wsI[idx], __ATOMIC_RELAXED,
                                              __HIP_MEMORY_SCOPE_AGENT);
            upd(sa, ia, sb, ib, s, i);
        }
#pragma unroll
        for (int m = 1; m < 64; m <<= 1) {
            float o1s = __shfl_xor(sa, m); int o1i = __shfl_xor(ia, m);
            float o2s = __shfl_xor(sb, m); int o2i = __shfl_xor(ib, m);
            merge2(sa, ia, sb, ib, o1s, o1i, o2s, o2i);
        }
        if (lane == 0) {
            g_s[g * 2 + 0] = sa; g_i[g * 2 + 0] = ia;
            g_s[g * 2 + 1] = sb; g_i[g * 2 + 1] = ib;
        }
    }
    __syncthreads();

    if (tid == 0) {
        // insertion sort, descending by (score, -idx) == the reference keep-order
        for (int a = 1; a < 16; ++a) {
            float s = g_s[a]; int ix = g_i[a];
            int b = a - 1;
            while (b >= 0 && better(s, ix, g_s[b], g_i[b])) {
                g_s[b + 1] = g_s[b]; g_i[b + 1] = g_i[b]; --b;
            }
            g_s[b + 1] = s; g_i[b + 1] = ix;
        }
    }
    __syncthreads();

    if (tid < 16) {
        const float scale[6] = {256.f, 256.f, 256.f, 256.f, 128.f, 128.f};
        const float stdv[6]  = {0.1f, 0.1f, 0.1f, 0.2f, 0.2f, 0.2f};
        const int flat = g_i[tid];
        const float score = g_s[tid];
        const int prop = flat >> 1;
        const int cls = (flat & 1) + 1;
        const int b = prop >> NA_LOG2;
        const int ar = prop & ((1 << NA_LOG2) - 1);   // anchors_rep index mod NA

        float anc[6], dlt[6];
#pragma unroll
        for (int k = 0; k < 6; ++k) {
            anc[k] = floorf(anchors[ar * 6 + k] / scale[k]);
            dlt[k] = deltas[prop * 6 + k] * stdv[k];
        }
        float h = anc[2] - anc[0];
        float w = anc[3] - anc[1];
        float d = anc[5] - anc[4];
        float cy = anc[0] + 0.5f * h + dlt[0] * h;
        float cx = anc[1] + 0.5f * w + dlt[1] * w;
        float cz = anc[4] + 0.5f * d + dlt[2] * d;
        h *= expf(dlt[3]);
        w *= expf(dlt[4]);
        d *= expf(dlt[5]);
        const float y1 = cy - 0.5f * h, x1 = cx - 0.5f * w, z1 = cz - 0.5f * d;
        const float box[6] = {y1, x1, y1 + h, x1 + w, z1, z1 + d};

        float* o = out + tid * 9;
#pragma unroll
        for (int k = 0; k < 6; ++k) {
            float bx = box[k] * scale[k];
            bx = fminf(fmaxf(bx, 0.f), scale[k]);
            o[k] = rintf(bx);               // jnp.round = round-half-to-even
        }
        o[6] = (float)b;
        o[7] = (float)cls;
        o[8] = score;
    }
}

extern "C" void kernel_launch(void* const* d_in, const int* in_sizes, int n_in,
                              void* d_out, int out_size, void* d_ws, size_t ws_size,
                              hipStream_t stream)
{
    // setup_inputs order: anchors, probs, deltas, batch_ixs
    const float* anchors = (const float*)d_in[0];
    const float* probs   = (const float*)d_in[1];
    const float* deltas  = (const float*)d_in[2];
    // batch_ixs (d_in[3]) is closed-form (prop >> 20); unused.

    float*        wsS     = (float*)d_ws;
    int*          wsI     = (int*)((char*)d_ws + WS_I_OFF);
    unsigned int* counter = (unsigned int*)((char*)d_ws + WS_COUNTER_OFF);

    // zero the completion counter (ws is poisoned 0xAA before every launch)
    hipMemsetAsync(counter, 0, sizeof(unsigned int), stream);

    topk_fused<<<dim3(B1), dim3(T1), 0, stream>>>(probs, anchors, deltas,
                                                  wsS, wsI, counter, (float*)d_out);
}

// Round 5
// 237.144 us; speedup vs baseline: 1.4021x; 1.0357x over previous
//
#include <hip/hip_runtime.h>
#include <float.h>
#include <math.h>

// Problem constants (from reference)
#define NA_LOG2 20                    // NA = 1048576
#define NB_ 4
#define ROWS (NB_ << NA_LOG2)         // 4194304 rows of probs (3 floats each)
#define B1 1024                       // blocks (256 per batch)
#define T1 256
#define ROWS_PER_BLOCK (ROWS / B1)    // 4096
#define SEGS_PER_BLOCK (ROWS_PER_BLOCK / 4)  // 1024 segments of 4 rows (48B)
#define BLOCKS_PER_BATCH (B1 / NB_)   // 256

// ws layout: wsS [0,16KB) floats, wsI [16KB,32KB) ints, counter at 32KB
#define WS_I_OFF       (B1 * 4 * sizeof(float))
#define WS_COUNTER_OFF (32 * 1024)

// strict total order: higher score wins, ties -> lower flat index
__device__ __forceinline__ bool better(float sa, int ia, float sb, int ib) {
    return (sa > sb) || ((sa == sb) && (ia < ib));
}

// BRANCHLESS top-2 insert (pure v_cmp/v_cndmask dataflow, single basic block)
__device__ __forceinline__ void upd(float& sa, int& ia, float& sb, int& ib,
                                    float s, int i)
{
    const bool b1 = better(s, i, sa, ia);   // beats first
    const bool b2 = better(s, i, sb, ib);   // beats second
    const float nbs = b1 ? sa : (b2 ? s : sb);
    const int   nbi = b1 ? ia : (b2 ? i : ib);
    sa = b1 ? s : sa;
    ia = b1 ? i : ia;
    sb = nbs;
    ib = nbi;
}

// BRANCHLESS merge of sorted pair (b1>=b2) into sorted pair (a1>=a2)
__device__ __forceinline__ void merge2(float& a1s, int& a1i, float& a2s, int& a2i,
                                       float b1s, int b1i, float b2s, int b2i)
{
    const bool t = better(b1s, b1i, a1s, a1i);
    const float n1s = t ? b1s : a1s;  const int n1i = t ? b1i : a1i;
    const float c1s = t ? a1s : b1s;  const int c1i = t ? a1i : b1i;  // loser of firsts
    const float c2s = t ? b2s : a2s;  const int c2i = t ? b2i : a2i;  // winner's second
    const bool u = better(c1s, c1i, c2s, c2i);
    a1s = n1s;               a1i = n1i;
    a2s = u ? c1s : c2s;     a2i = u ? c1i : c2i;
}

// Fused: per-block top-2 (class1, class2), publish to ws, last block finishes.
// Rounds 2-4 all showed VGPR_Count 16-24: the list scheduler sinks every
// global load to its consumer (1 load in flight -> ~0.5 TB/s). sched_barrier(0)
// pins all 12 loads BEFORE any consumer so they are simultaneously in flight.
__global__ __launch_bounds__(T1, 4) void topk_fused(const float* __restrict__ probs,
                                                    const float* __restrict__ anchors,
                                                    const float* __restrict__ deltas,
                                                    float* __restrict__ wsS,
                                                    int* __restrict__ wsI,
                                                    unsigned int* __restrict__ counter,
                                                    float* __restrict__ out)
{
    const int tid = threadIdx.x;
    const int bb = blockIdx.x;

    float s1a = -FLT_MAX, s1b = -FLT_MAX, s2a = -FLT_MAX, s2b = -FLT_MAX;
    int   i1a = 0x7fffffff, i1b = 0x7fffffff, i2a = 0x7fffffff, i2b = 0x7fffffff;

    const float4* p4 = (const float4*)probs;
    const int s_base = bb * SEGS_PER_BLOCK;

    // addresses first, then ALL 12 loads, then a hard scheduling fence
    const float4* pA = p4 + (long)(s_base + 0 * T1 + tid) * 3;
    const float4* pB = p4 + (long)(s_base + 1 * T1 + tid) * 3;
    const float4* pC = p4 + (long)(s_base + 2 * T1 + tid) * 3;
    const float4* pD = p4 + (long)(s_base + 3 * T1 + tid) * 3;

    float4 v0 = pA[0], v1  = pA[1], v2  = pA[2];
    float4 v3 = pB[0], v4  = pB[1], v5  = pB[2];
    float4 v6 = pC[0], v7  = pC[1], v8  = pC[2];
    float4 v9 = pD[0], v10 = pD[1], v11 = pD[2];

    // nothing may cross this point: all 12 global_load_dwordx4 issue first,
    // waitcnt insertion then emits progressive vmcnt(N) before each use
    __builtin_amdgcn_sched_barrier(0);

    // consume: segment floats idx 0..11 -> row=idx/3, col=idx%3 (col1/2 = fg)
#pragma unroll
    for (int k = 0; k < 4; ++k) {
        const int seg = s_base + k * T1 + tid;
        const int f0 = seg * 8;                      // 4 rows x 2 fg classes
        const float4 a = (k == 0) ? v0 : (k == 1) ? v3 : (k == 2) ? v6 : v9;
        const float4 b = (k == 0) ? v1 : (k == 1) ? v4 : (k == 2) ? v7 : v10;
        const float4 c = (k == 0) ? v2 : (k == 1) ? v5 : (k == 2) ? v8 : v11;
        upd(s1a, i1a, s1b, i1b, a.y, f0 + 0);   // r0 class1
        upd(s2a, i2a, s2b, i2b, a.z, f0 + 1);   // r0 class2
        upd(s1a, i1a, s1b, i1b, b.x, f0 + 2);   // r1 class1
        upd(s2a, i2a, s2b, i2b, b.y, f0 + 3);   // r1 class2
        upd(s1a, i1a, s1b, i1b, b.w, f0 + 4);   // r2 class1
        upd(s2a, i2a, s2b, i2b, c.x, f0 + 5);   // r2 class2
        upd(s1a, i1a, s1b, i1b, c.z, f0 + 6);   // r3 class1
        upd(s2a, i2a, s2b, i2b, c.w, f0 + 7);   // r3 class2
    }

    // wave (64-lane) butterfly reduce of both top2 structs (branchless merges)
#pragma unroll
    for (int m = 1; m < 64; m <<= 1) {
        float o1s = __shfl_xor(s1a, m); int o1i = __shfl_xor(i1a, m);
        float o2s = __shfl_xor(s1b, m); int o2i = __shfl_xor(i1b, m);
        merge2(s1a, i1a, s1b, i1b, o1s, o1i, o2s, o2i);
        o1s = __shfl_xor(s2a, m); o1i = __shfl_xor(i2a, m);
        o2s = __shfl_xor(s2b, m); o2i = __shfl_xor(i2b, m);
        merge2(s2a, i2a, s2b, i2b, o1s, o1i, o2s, o2i);
    }

    __shared__ float ls[4][4];
    __shared__ int   li[4][4];
    __shared__ int   amLast;
    const int wave = tid >> 6, lane = tid & 63;
    if (lane == 0) {
        ls[wave][0] = s1a; li[wave][0] = i1a;
        ls[wave][1] = s1b; li[wave][1] = i1b;
        ls[wave][2] = s2a; li[wave][2] = i2a;
        ls[wave][3] = s2b; li[wave][3] = i2b;
    }
    __syncthreads();
    if (tid == 0) {
        for (int wv = 1; wv < 4; ++wv) {
            merge2(s1a, i1a, s1b, i1b, ls[wv][0], li[wv][0], ls[wv][1], li[wv][1]);
            merge2(s2a, i2a, s2b, i2b, ls[wv][2], li[wv][2], ls[wv][3], li[wv][3]);
        }
        const int base = bb * 4;
        // agent-scope stores: visible across XCDs for the last block's read
        __hip_atomic_store(&wsS[base + 0], s1a, __ATOMIC_RELAXED, __HIP_MEMORY_SCOPE_AGENT);
        __hip_atomic_store(&wsI[base + 0], i1a, __ATOMIC_RELAXED, __HIP_MEMORY_SCOPE_AGENT);
        __hip_atomic_store(&wsS[base + 1], s1b, __ATOMIC_RELAXED, __HIP_MEMORY_SCOPE_AGENT);
        __hip_atomic_store(&wsI[base + 1], i1b, __ATOMIC_RELAXED, __HIP_MEMORY_SCOPE_AGENT);
        __hip_atomic_store(&wsS[base + 2], s2a, __ATOMIC_RELAXED, __HIP_MEMORY_SCOPE_AGENT);
        __hip_atomic_store(&wsI[base + 2], i2a, __ATOMIC_RELAXED, __HIP_MEMORY_SCOPE_AGENT);
        __hip_atomic_store(&wsS[base + 3], s2b, __ATOMIC_RELAXED, __HIP_MEMORY_SCOPE_AGENT);
        __hip_atomic_store(&wsI[base + 3], i2b, __ATOMIC_RELAXED, __HIP_MEMORY_SCOPE_AGENT);
        __threadfence();  // release before signaling
        unsigned int old = __hip_atomic_fetch_add(counter, 1u, __ATOMIC_ACQ_REL,
                                                  __HIP_MEMORY_SCOPE_AGENT);
        amLast = (old == (unsigned)(B1 - 1)) ? 1 : 0;
    }
    __syncthreads();
    if (!amLast) return;

    // ===== last block: final reduce over B1*4 candidates, sort, epilogue =====
    __threadfence();  // acquire side

    __shared__ float g_s[16];
    __shared__ int   g_i[16];

    // 4 waves, each handles 2 of the 8 (batch,class) groups; 512 candidates/group
#pragma unroll
    for (int grp2 = 0; grp2 < 2; ++grp2) {
        const int g = wave * 2 + grp2;
        const int batch = g >> 1, clsbit = g & 1;
        float sa = -FLT_MAX, sb = -FLT_MAX;
        int   ia = 0x7fffffff, ib = 0x7fffffff;
#pragma unroll
        for (int j = 0; j < (2 * BLOCKS_PER_BATCH) / 64; ++j) {  // 8 candidates/lane
            const int q = lane + j * 64;                          // 0..511
            const int blk = batch * BLOCKS_PER_BATCH + (q >> 1);
            const int e = q & 1;
            const int idx = blk * 4 + clsbit * 2 + e;
            const float s = __hip_atomic_load(&wsS[idx], __ATOMIC_RELAXED,
                                              __HIP_MEMORY_SCOPE_AGENT);
            const int   i = __hip_atomic_load(&wsI[idx], __ATOMIC_RELAXED,
                                              __HIP_MEMORY_SCOPE_AGENT);
            upd(sa, ia, sb, ib, s, i);
        }
#pragma unroll
        for (int m = 1; m < 64; m <<= 1) {
            float o1s = __shfl_xor(sa, m); int o1i = __shfl_xor(ia, m);
            float o2s = __shfl_xor(sb, m); int o2i = __shfl_xor(ib, m);
            merge2(sa, ia, sb, ib, o1s, o1i, o2s, o2i);
        }
        if (lane == 0) {
            g_s[g * 2 + 0] = sa; g_i[g * 2 + 0] = ia;
            g_s[g * 2 + 1] = sb; g_i[g * 2 + 1] = ib;
        }
    }
    __syncthreads();

    if (tid == 0) {
        // insertion sort, descending by (score, -idx) == the reference keep-order
        for (int a = 1; a < 16; ++a) {
            float s = g_s[a]; int ix = g_i[a];
            int b = a - 1;
            while (b >= 0 && better(s, ix, g_s[b], g_i[b])) {
                g_s[b + 1] = g_s[b]; g_i[b + 1] = g_i[b]; --b;
            }
            g_s[b + 1] = s; g_i[b + 1] = ix;
        }
    }
    __syncthreads();

    if (tid < 16) {
        const float scale[6] = {256.f, 256.f, 256.f, 256.f, 128.f, 128.f};
        const float stdv[6]  = {0.1f, 0.1f, 0.1f, 0.2f, 0.2f, 0.2f};
        const int flat = g_i[tid];
        const float score = g_s[tid];
        const int prop = flat >> 1;
        const int cls = (flat & 1) + 1;
        const int b = prop >> NA_LOG2;
        const int ar = prop & ((1 << NA_LOG2) - 1);   // anchors_rep index mod NA

        float anc[6], dlt[6];
#pragma unroll
        for (int k = 0; k < 6; ++k) {
            anc[k] = floorf(anchors[ar * 6 + k] / scale[k]);
            dlt[k] = deltas[prop * 6 + k] * stdv[k];
        }
        float h = anc[2] - anc[0];
        float w = anc[3] - anc[1];
        float d = anc[5] - anc[4];
        float cy = anc[0] + 0.5f * h + dlt[0] * h;
        float cx = anc[1] + 0.5f * w + dlt[1] * w;
        float cz = anc[4] + 0.5f * d + dlt[2] * d;
        h *= expf(dlt[3]);
        w *= expf(dlt[4]);
        d *= expf(dlt[5]);
        const float y1 = cy - 0.5f * h, x1 = cx - 0.5f * w, z1 = cz - 0.5f * d;
        const float box[6] = {y1, x1, y1 + h, x1 + w, z1, z1 + d};

        float* o = out + tid * 9;
#pragma unroll
        for (int k = 0; k < 6; ++k) {
            float bx = box[k] * scale[k];
            bx = fminf(fmaxf(bx, 0.f), scale[k]);
            o[k] = rintf(bx);               // jnp.round = round-half-to-even
        }
        o[6] = (float)b;
        o[7] = (float)cls;
        o[8] = score;
    }
}

extern "C" void kernel_launch(void* const* d_in, const int* in_sizes, int n_in,
                              void* d_out, int out_size, void* d_ws, size_t ws_size,
                              hipStream_t stream)
{
    // setup_inputs order: anchors, probs, deltas, batch_ixs
    const float* anchors = (const float*)d_in[0];
    const float* probs   = (const float*)d_in[1];
    const float* deltas  = (const float*)d_in[2];
    // batch_ixs (d_in[3]) is closed-form (prop >> 20); unused.

    float*        wsS     = (float*)d_ws;
    int*          wsI     = (int*)((char*)d_ws + WS_I_OFF);
    unsigned int* counter = (unsigned int*)((char*)d_ws + WS_COUNTER_OFF);

    // zero the completion counter (ws is poisoned 0xAA before every launch)
    hipMemsetAsync(counter, 0, sizeof(unsigned int), stream);

    topk_fused<<<dim3(B1), dim3(T1), 0, stream>>>(probs, anchors, deltas,
                                                  wsS, wsI, counter, (float*)d_out);
}

// Round 6
// 185.018 us; speedup vs baseline: 1.7971x; 1.2817x over previous
//
#include <hip/hip_runtime.h>
#include <float.h>
#include <math.h>

// Problem constants (from reference)
#define NA_LOG2 20                     // NA = 1048576
#define NB_ 4
#define ROWS (NB_ << NA_LOG2)          // 4194304 rows of probs (3 floats each)
#define B1 1024                        // pass-1 blocks (256 per batch)
#define T1 256
#define F4_PER_BLOCK 3072              // 48 KB per block as float4
#define F4_PER_THREAD (F4_PER_BLOCK / T1)   // 12
#define BLOCKS_PER_BATCH (B1 / NB_)    // 256

typedef unsigned long long u64;
typedef unsigned int u32;

// key = (score_bits << 32) | ~fg_index. Scores are softmax outputs (>0), so
// float bit pattern is monotone in value; key desc == (score desc, idx asc),
// exactly the reference's keep-order. Sentinel/worst key = 0.

// branchless top-2 insert on keys
__device__ __forceinline__ void upd2(u64& ka, u64& kb, u64 k) {
    const bool b1 = k > ka;
    const bool b2 = k > kb;
    kb = b1 ? ka : (b2 ? k : kb);
    ka = b1 ? k : ka;
}

// branchless merge of sorted pair (b1>=b2) into sorted pair (a1>=a2)
__device__ __forceinline__ void mrg2(u64& a1, u64& a2, u64 b1, u64 b2) {
    const bool t = b1 > a1;
    const u64 n1 = t ? b1 : a1;
    const u64 c1 = t ? a1 : b1;   // loser of firsts
    const u64 c2 = t ? b2 : a2;   // winner's second
    a2 = (c1 > c2) ? c1 : c2;
    a1 = n1;
}

// Pass 1: fully-coalesced scan (lane i reads float4 at 16*i — the m13 pattern
// that reaches 6.3 TB/s; rounds 2-5's 48B-strided dwordx4 got 0.5 TB/s).
// Row/col structure recovered arithmetically: fi -> row=fi/3, col=fi%3.
__global__ __launch_bounds__(T1) void scan_pass1(const float4* __restrict__ p4,
                                                 u64* __restrict__ wsK)
{
    const int tid = threadIdx.x;
    const int bb  = blockIdx.x;
    const int base = bb * F4_PER_BLOCK;

    u64 k1a = 0, k1b = 0, k2a = 0, k2b = 0;   // top2 class1, top2 class2

#pragma unroll
    for (int k = 0; k < F4_PER_THREAD; ++k) {
        const int u = base + k * T1 + tid;     // absolute float4 index
        const float4 v = p4[u];
        const int fi0 = u * 4;                 // absolute float index (< 2^24)
        const int r0  = fi0 / 3;               // compiler magic-mul
        const int ph  = fi0 - r0 * 3;          // phase 0..2
#pragma unroll
        for (int j = 0; j < 4; ++j) {
            const float s = (j == 0) ? v.x : (j == 1) ? v.y : (j == 2) ? v.z : v.w;
            const int  cj   = ph + j;          // 0..5
            const bool wrap = (cj >= 3);
            const int  col  = wrap ? cj - 3 : cj;
            const int  row  = r0 + (wrap ? 1 : 0);
            const int  fg   = 2 * row + (col - 1);   // valid only for col 1/2
            const u64  key  = ((u64)__float_as_uint(s) << 32) | (u32)~(u32)fg;
            upd2(k1a, k1b, (col == 1) ? key : 0ull);
            upd2(k2a, k2b, (col == 2) ? key : 0ull);
        }
    }

    // 64-lane butterfly reduce of both top2 pairs
#pragma unroll
    for (int m = 1; m < 64; m <<= 1) {
        u64 o1 = (u64)__shfl_xor((long long)k1a, m);
        u64 o2 = (u64)__shfl_xor((long long)k1b, m);
        mrg2(k1a, k1b, o1, o2);
        o1 = (u64)__shfl_xor((long long)k2a, m);
        o2 = (u64)__shfl_xor((long long)k2b, m);
        mrg2(k2a, k2b, o1, o2);
    }

    __shared__ u64 ls[4][4];
    const int wave = tid >> 6, lane = tid & 63;
    if (lane == 0) {
        ls[wave][0] = k1a; ls[wave][1] = k1b;
        ls[wave][2] = k2a; ls[wave][3] = k2b;
    }
    __syncthreads();
    if (tid == 0) {
        for (int wv = 1; wv < 4; ++wv) {
            mrg2(k1a, k1b, ls[wv][0], ls[wv][1]);
            mrg2(k2a, k2b, ls[wv][2], ls[wv][3]);
        }
        u64* o = wsK + bb * 4;
        o[0] = k1a; o[1] = k1b; o[2] = k2a; o[3] = k2b;
        // plain stores: kernel-end release makes them visible to pass 2
    }
}

// Pass 2: one block, 512 threads = 8 waves; wave g reduces group g
// (batch=g>>1, class bit=g&1) over its 512 block-candidates; thread 0 sorts
// the 16 winners desc (== keep order); 16 threads emit the output rows.
__global__ __launch_bounds__(512) void finish_pass2(const u64* __restrict__ wsK,
                                                    const float* __restrict__ anchors,
                                                    const float* __restrict__ deltas,
                                                    float* __restrict__ out)
{
    __shared__ u64 g_k[16];
    const int tid = threadIdx.x;
    const int wave = tid >> 6, lane = tid & 63;
    const int batch = wave >> 1, clsbit = wave & 1;

    u64 ka = 0, kb = 0;
#pragma unroll
    for (int j = 0; j < (2 * BLOCKS_PER_BATCH) / 64; ++j) {   // 8 candidates/lane
        const int q   = j * 64 + lane;                         // 0..511
        const int blk = batch * BLOCKS_PER_BATCH + (q >> 1);
        const int e   = q & 1;
        upd2(ka, kb, wsK[blk * 4 + clsbit * 2 + e]);
    }
#pragma unroll
    for (int m = 1; m < 64; m <<= 1) {
        u64 o1 = (u64)__shfl_xor((long long)ka, m);
        u64 o2 = (u64)__shfl_xor((long long)kb, m);
        mrg2(ka, kb, o1, o2);
    }
    if (lane == 0) {
        g_k[wave * 2 + 0] = ka;
        g_k[wave * 2 + 1] = kb;
    }
    __syncthreads();

    if (tid == 0) {
        // insertion sort desc on u64 keys == (score desc, idx asc) == keep order
        for (int a = 1; a < 16; ++a) {
            const u64 kv = g_k[a];
            int b = a - 1;
            while (b >= 0 && kv > g_k[b]) { g_k[b + 1] = g_k[b]; --b; }
            g_k[b + 1] = kv;
        }
    }
    __syncthreads();

    if (tid < 16) {
        const float scale[6] = {256.f, 256.f, 256.f, 256.f, 128.f, 128.f};
        const float stdv[6]  = {0.1f, 0.1f, 0.1f, 0.2f, 0.2f, 0.2f};
        const u64 key = g_k[tid];
        const float score = __uint_as_float((u32)(key >> 32));
        const int flat = (int)~(u32)key;              // fg flat index
        const int prop = flat >> 1;
        const int cls  = (flat & 1) + 1;
        const int b    = prop >> NA_LOG2;
        const int ar   = prop & ((1 << NA_LOG2) - 1); // anchors_rep index mod NA

        float anc[6], dlt[6];
#pragma unroll
        for (int k = 0; k < 6; ++k) {
            anc[k] = floorf(anchors[ar * 6 + k] / scale[k]);
            dlt[k] = deltas[prop * 6 + k] * stdv[k];
        }
        float h = anc[2] - anc[0];
        float w = anc[3] - anc[1];
        float d = anc[5] - anc[4];
        float cy = anc[0] + 0.5f * h + dlt[0] * h;
        float cx = anc[1] + 0.5f * w + dlt[1] * w;
        float cz = anc[4] + 0.5f * d + dlt[2] * d;
        h *= expf(dlt[3]);
        w *= expf(dlt[4]);
        d *= expf(dlt[5]);
        const float y1 = cy - 0.5f * h, x1 = cx - 0.5f * w, z1 = cz - 0.5f * d;
        const float box[6] = {y1, x1, y1 + h, x1 + w, z1, z1 + d};

        float* o = out + tid * 9;
#pragma unroll
        for (int k = 0; k < 6; ++k) {
            float bx = box[k] * scale[k];
            bx = fminf(fmaxf(bx, 0.f), scale[k]);
            o[k] = rintf(bx);               // jnp.round = round-half-to-even
        }
        o[6] = (float)b;
        o[7] = (float)cls;
        o[8] = score;
    }
}

extern "C" void kernel_launch(void* const* d_in, const int* in_sizes, int n_in,
                              void* d_out, int out_size, void* d_ws, size_t ws_size,
                              hipStream_t stream)
{
    // setup_inputs order: anchors, probs, deltas, batch_ixs
    const float* anchors = (const float*)d_in[0];
    const float* probs   = (const float*)d_in[1];
    const float* deltas  = (const float*)d_in[2];
    // batch_ixs (d_in[3]) is closed-form (prop >> 20); unused.

    u64* wsK = (u64*)d_ws;   // 1024 blocks x 4 keys = 32 KB

    scan_pass1<<<dim3(B1), dim3(T1), 0, stream>>>((const float4*)probs, wsK);
    finish_pass2<<<dim3(1), dim3(512), 0, stream>>>(wsK, anchors, deltas, (float*)d_out);
}

// Round 7
// 184.067 us; speedup vs baseline: 1.8063x; 1.0052x over previous
//
#include <hip/hip_runtime.h>
#include <float.h>
#include <math.h>

// Problem constants (from reference)
#define NA_LOG2 20                     // NA = 1048576
#define NB_ 4
#define B1 2048                        // pass-1 blocks (512 per batch)
#define T1 256
#define BYTES_PER_BLOCK 24576          // 24 KB slice of probs per block
#define CHUNKS 6                       // 6 x 256 threads x 16B = 24576
#define SEGS 512                       // 24576 / 48B (4 rows) per block
#define SEGS_PER_THREAD 2
#define BLOCKS_PER_BATCH (B1 / NB_)    // 512

typedef unsigned long long u64;
typedef unsigned int u32;

// key = (score_bits << 32) | ~fg_index. Softmax scores are > 0, so the f32 bit
// pattern is monotone in value; key desc == (score desc, idx asc) == the
// reference keep-order. Sentinel/worst key = 0 (real keys have hi >= 1).

// branchless top-2 insert on keys
__device__ __forceinline__ void upd2(u64& ka, u64& kb, u64 k) {
    const bool b1 = k > ka;
    const bool b2 = k > kb;
    kb = b1 ? ka : (b2 ? k : kb);
    ka = b1 ? k : ka;
}

// branchless merge of sorted pair (b1>=b2) into sorted pair (a1>=a2)
__device__ __forceinline__ void mrg2(u64& a1, u64& a2, u64 b1, u64 b2) {
    const bool t = b1 > a1;
    const u64 n1 = t ? b1 : a1;
    const u64 c1 = t ? a1 : b1;   // loser of firsts
    const u64 c2 = t ? b2 : a2;   // winner's second
    a2 = (c1 > c2) ? c1 : c2;
    a1 = n1;
}

// Pass 1: async global->LDS staging (global_load_lds has no VGPR destination,
// so the list scheduler cannot sink it to a consumer — the serialization that
// pinned rounds 2-5 at 0.5 TB/s with VGPR_Count 16-24). 6 copies in flight per
// lane; __syncthreads drains vmcnt; consume from LDS in row-aligned segments.
__global__ __launch_bounds__(T1) void scan_pass1(const char* __restrict__ probs,
                                                 u64* __restrict__ wsK)
{
    __shared__ __align__(16) char smem[BYTES_PER_BLOCK];
    __shared__ u64 ls[4][4];

    const int tid = threadIdx.x;
    const int bb  = blockIdx.x;
    const char* gbase = probs + (size_t)bb * BYTES_PER_BLOCK;

    // stage 24 KB: chunk c, thread t -> lds offset (c*256+t)*16, same global
    // offset. Within a wave: lds = uniform + lane*16 (required layout).
#pragma unroll
    for (int c = 0; c < CHUNKS; ++c) {
        const int off = (c * T1 + tid) * 16;
        __builtin_amdgcn_global_load_lds(
            (const __attribute__((address_space(1))) void*)(gbase + off),
            (__attribute__((address_space(3))) void*)(smem + off),
            16, 0, 0);
    }
    __syncthreads();   // compiler emits s_waitcnt vmcnt(0) before s_barrier

    const float4* sm4 = (const float4*)smem;
    u64 k1a = 0, k1b = 0, k2a = 0, k2b = 0;   // top2 class1, top2 class2

    // segment = 4 rows = 12 floats: [r0c0 r0c1 r0c2 r1c0][r1c1 r1c2 r2c0 r2c1][r2c2 r3c0 r3c1 r3c2]
#pragma unroll
    for (int k = 0; k < SEGS_PER_THREAD; ++k) {
        const int seg = k * T1 + tid;              // 0..511
        const float4 a = sm4[seg * 3 + 0];
        const float4 b = sm4[seg * 3 + 1];
        const float4 c = sm4[seg * 3 + 2];
        const u32 f0  = ((u32)(bb * SEGS + seg)) * 8;   // fg flat base
        const u32 nf0 = ~f0;                             // ~(f0+e) == nf0 - e
        upd2(k1a, k1b, ((u64)__float_as_uint(a.y) << 32) | (u64)(nf0 - 0));  // r0 c1
        upd2(k2a, k2b, ((u64)__float_as_uint(a.z) << 32) | (u64)(nf0 - 1));  // r0 c2
        upd2(k1a, k1b, ((u64)__float_as_uint(b.x) << 32) | (u64)(nf0 - 2));  // r1 c1
        upd2(k2a, k2b, ((u64)__float_as_uint(b.y) << 32) | (u64)(nf0 - 3));  // r1 c2
        upd2(k1a, k1b, ((u64)__float_as_uint(b.w) << 32) | (u64)(nf0 - 4));  // r2 c1
        upd2(k2a, k2b, ((u64)__float_as_uint(c.x) << 32) | (u64)(nf0 - 5));  // r2 c2
        upd2(k1a, k1b, ((u64)__float_as_uint(c.z) << 32) | (u64)(nf0 - 6));  // r3 c1
        upd2(k2a, k2b, ((u64)__float_as_uint(c.w) << 32) | (u64)(nf0 - 7));  // r3 c2
    }

    // 64-lane butterfly reduce of both top2 pairs
#pragma unroll
    for (int m = 1; m < 64; m <<= 1) {
        u64 o1 = (u64)__shfl_xor((long long)k1a, m);
        u64 o2 = (u64)__shfl_xor((long long)k1b, m);
        mrg2(k1a, k1b, o1, o2);
        o1 = (u64)__shfl_xor((long long)k2a, m);
        o2 = (u64)__shfl_xor((long long)k2b, m);
        mrg2(k2a, k2b, o1, o2);
    }

    const int wave = tid >> 6, lane = tid & 63;
    if (lane == 0) {
        ls[wave][0] = k1a; ls[wave][1] = k1b;
        ls[wave][2] = k2a; ls[wave][3] = k2b;
    }
    __syncthreads();
    if (tid == 0) {
        for (int wv = 1; wv < 4; ++wv) {
            mrg2(k1a, k1b, ls[wv][0], ls[wv][1]);
            mrg2(k2a, k2b, ls[wv][2], ls[wv][3]);
        }
        u64* o = wsK + bb * 4;
        o[0] = k1a; o[1] = k1b; o[2] = k2a; o[3] = k2b;
        // plain stores: kernel-end release makes them visible to pass 2
    }
}

// Pass 2: one block, 512 threads = 8 waves; wave g reduces group g
// (batch=g>>1, class bit=g&1) over its 1024 block-candidates; thread 0 sorts
// the 16 winners desc (== keep order); 16 threads emit the output rows.
__global__ __launch_bounds__(512) void finish_pass2(const u64* __restrict__ wsK,
                                                    const float* __restrict__ anchors,
                                                    const float* __restrict__ deltas,
                                                    float* __restrict__ out)
{
    __shared__ u64 g_k[16];
    const int tid = threadIdx.x;
    const int wave = tid >> 6, lane = tid & 63;
    const int batch = wave >> 1, clsbit = wave & 1;

    u64 ka = 0, kb = 0;
#pragma unroll
    for (int j = 0; j < (2 * BLOCKS_PER_BATCH) / 64; ++j) {   // 16 candidates/lane
        const int q   = j * 64 + lane;                         // 0..1023
        const int blk = batch * BLOCKS_PER_BATCH + (q >> 1);
        const int e   = q & 1;
        upd2(ka, kb, wsK[blk * 4 + clsbit * 2 + e]);
    }
#pragma unroll
    for (int m = 1; m < 64; m <<= 1) {
        u64 o1 = (u64)__shfl_xor((long long)ka, m);
        u64 o2 = (u64)__shfl_xor((long long)kb, m);
        mrg2(ka, kb, o1, o2);
    }
    if (lane == 0) {
        g_k[wave * 2 + 0] = ka;
        g_k[wave * 2 + 1] = kb;
    }
    __syncthreads();

    if (tid == 0) {
        // insertion sort desc on u64 keys == (score desc, idx asc) == keep order
        for (int a = 1; a < 16; ++a) {
            const u64 kv = g_k[a];
            int b = a - 1;
            while (b >= 0 && kv > g_k[b]) { g_k[b + 1] = g_k[b]; --b; }
            g_k[b + 1] = kv;
        }
    }
    __syncthreads();

    if (tid < 16) {
        const float scale[6] = {256.f, 256.f, 256.f, 256.f, 128.f, 128.f};
        const float stdv[6]  = {0.1f, 0.1f, 0.1f, 0.2f, 0.2f, 0.2f};
        const u64 key = g_k[tid];
        const float score = __uint_as_float((u32)(key >> 32));
        const int flat = (int)~(u32)key;              // fg flat index
        const int prop = flat >> 1;
        const int cls  = (flat & 1) + 1;
        const int b    = prop >> NA_LOG2;
        const int ar   = prop & ((1 << NA_LOG2) - 1); // anchors_rep index mod NA

        float anc[6], dlt[6];
#pragma unroll
        for (int k = 0; k < 6; ++k) {
            anc[k] = floorf(anchors[ar * 6 + k] / scale[k]);
            dlt[k] = deltas[prop * 6 + k] * stdv[k];
        }
        float h = anc[2] - anc[0];
        float w = anc[3] - anc[1];
        float d = anc[5] - anc[4];
        float cy = anc[0] + 0.5f * h + dlt[0] * h;
        float cx = anc[1] + 0.5f * w + dlt[1] * w;
        float cz = anc[4] + 0.5f * d + dlt[2] * d;
        h *= expf(dlt[3]);
        w *= expf(dlt[4]);
        d *= expf(dlt[5]);
        const float y1 = cy - 0.5f * h, x1 = cx - 0.5f * w, z1 = cz - 0.5f * d;
        const float box[6] = {y1, x1, y1 + h, x1 + w, z1, z1 + d};

        float* o = out + tid * 9;
#pragma unroll
        for (int k = 0; k < 6; ++k) {
            float bx = box[k] * scale[k];
            bx = fminf(fmaxf(bx, 0.f), scale[k]);
            o[k] = rintf(bx);               // jnp.round = round-half-to-even
        }
        o[6] = (float)b;
        o[7] = (float)cls;
        o[8] = score;
    }
}

extern "C" void kernel_launch(void* const* d_in, const int* in_sizes, int n_in,
                              void* d_out, int out_size, void* d_ws, size_t ws_size,
                              hipStream_t stream)
{
    // setup_inputs order: anchors, probs, deltas, batch_ixs
    const float* anchors = (const float*)d_in[0];
    const float* probs   = (const float*)d_in[1];
    const float* deltas  = (const float*)d_in[2];
    // batch_ixs (d_in[3]) is closed-form (prop >> 20); unused.

    u64* wsK = (u64*)d_ws;   // 2048 blocks x 4 keys = 64 KB

    scan_pass1<<<dim3(B1), dim3(T1), 0, stream>>>((const char*)probs, wsK);
    finish_pass2<<<dim3(1), dim3(512), 0, stream>>>(wsK, anchors, deltas, (float*)d_out);
}